// Round 3
// baseline (3105.844 us; speedup 1.0000x reference)
//
#include <hip/hip_runtime.h>
#include <hip/hip_bf16.h>
#include <stdint.h>

static constexpr int O_TOT  = 28672;
static constexpr int K_TOT  = 8192;
static constexpr int M_ROWS = 8;
static constexpr int KW     = K_TOT / 8;   // 1024 packed int32 words per output row

// mode: 0 = bf16, 1 = fp16, 2 = f32 (16-bit tensors decoded per mode)
__device__ __forceinline__ float dec16(uint16_t u, int mode) {
  if (mode == 0) {
    union { uint32_t i; float f; } v; v.i = ((uint32_t)u) << 16; return v.f;
  } else {
    union { uint16_t u; _Float16 h; } v; v.u = u; return (float)v.h;
  }
}

// --- dtype sniffer: classify x's bit statistics, write mode flag to d_ws ---
__global__ void sniff_kernel(const uint16_t* __restrict__ x, int* __restrict__ flag) {
  const int t = threadIdx.x;          // one wave (64)
  int ce = 0, co = 0;                 // bf16-exponent-band hits, even/odd halves
  for (int i = t; i < 4096; i += 64) {
    const uint16_t ue = x[2*i];
    const uint16_t uo = x[2*i + 1];
    const int ee = (ue >> 7) & 0xFF;
    const int eo = (uo >> 7) & 0xFF;
    if (ee >= 118 && ee <= 131) ce++;
    if (eo >= 118 && eo <= 131) co++;
  }
  for (int d = 32; d; d >>= 1) {
    ce += __shfl_xor(ce, d);
    co += __shfl_xor(co, d);
  }
  if (t == 0) {
    // bf16: both parities ~99.8% in band; f32: odd(high half)~99.8%, even~5%;
    // fp16: both ~38%.
    int mode;
    if (ce > 2867 && co > 2867)      mode = 0;   // bf16
    else if (co > 2867)              mode = 2;   // f32
    else                             mode = 1;   // fp16
    *flag = mode;
  }
}

// --- probe kernel: one wave per output column, scalar everything ---
__global__ void wq_probe_kernel(const uint16_t* __restrict__ x16,
                                const uint32_t* __restrict__ qweight,
                                const uint32_t* __restrict__ qzeros,
                                const uint16_t* __restrict__ sc16,
                                const uint16_t* __restrict__ b16,
                                void* __restrict__ outv,
                                const int* __restrict__ flag)
{
  const int mode = *flag;                    // uniform
  const int o = blockIdx.x;                  // output column
  const int l = threadIdx.x;                 // lane 0..63
  const float* xf  = (const float*)x16;      // used only in mode 2
  const float* scf = (const float*)sc16;
  const float* bf  = (const float*)b16;

  float acc[M_ROWS];
  #pragma unroll
  for (int n = 0; n < M_ROWS; ++n) acc[n] = 0.f;

  for (int i = 0; i < 16; ++i) {
    const int w = l + 64 * i;                               // word 0..1023
    const uint32_t wv = qweight[(size_t)o * KW + w];
    const int g = w >> 4;                                   // quant group
    const uint32_t zw = qzeros[o * 8 + (g >> 3)];
    const float z = (float)((zw >> ((g & 7) * 4)) & 15u);
    const float s = (mode == 2) ? scf[o * 64 + g]
                                : dec16(sc16[o * 64 + g], mode);
    for (int j = 0; j < 8; ++j) {
      const float q = (float)((wv >> (4 * j)) & 15u);
      const float wgt = s * (q - z);
      const int k = 8 * w + j;
      for (int n = 0; n < M_ROWS; ++n) {
        const float xv = (mode == 2) ? xf[(size_t)n * K_TOT + k]
                                     : dec16(x16[(size_t)n * K_TOT + k], mode);
        acc[n] = fmaf(wgt, xv, acc[n]);
      }
    }
  }

  for (int n = 0; n < M_ROWS; ++n) {
    float v = acc[n];
    v += __shfl_xor(v, 32);
    v += __shfl_xor(v, 16);
    v += __shfl_xor(v, 8);
    v += __shfl_xor(v, 4);
    v += __shfl_xor(v, 2);
    v += __shfl_xor(v, 1);
    if (l == 0) {
      const float b = (mode == 2) ? bf[o] : dec16(b16[o], mode);
      const float r = v + b;
      const size_t idx = (size_t)n * O_TOT + o;
      if (mode == 0) {
        ((__hip_bfloat16*)outv)[idx] = __float2bfloat16(r);
      } else if (mode == 1) {
        union { uint16_t u; _Float16 h; } c; c.h = (_Float16)r;
        ((uint16_t*)outv)[idx] = c.u;
      } else {
        ((float*)outv)[idx] = r;
      }
    }
  }
}

extern "C" void kernel_launch(void* const* d_in, const int* in_sizes, int n_in,
                              void* d_out, int out_size, void* d_ws, size_t ws_size,
                              hipStream_t stream)
{
  const uint16_t* x       = (const uint16_t*)d_in[0];
  const uint32_t* qweight = (const uint32_t*)d_in[1];
  const uint32_t* qzeros  = (const uint32_t*)d_in[2];
  const uint16_t* scales  = (const uint16_t*)d_in[3];
  const uint16_t* bias    = (const uint16_t*)d_in[4];
  int* flag = (int*)d_ws;

  hipLaunchKernelGGL(sniff_kernel, dim3(1), dim3(64), 0, stream, x, flag);
  hipLaunchKernelGGL(wq_probe_kernel, dim3(O_TOT), dim3(64), 0, stream,
                     x, qweight, qzeros, scales, bias, d_out, flag);
}

// Round 4
// 162.444 us; speedup vs baseline: 19.1195x; 19.1195x over previous
//
#include <hip/hip_runtime.h>
#include <hip/hip_bf16.h>
#include <stdint.h>

static constexpr int O_TOT   = 28672;
static constexpr int K_TOT   = 8192;
static constexpr int M_ROWS  = 8;
static constexpr int KW      = K_TOT / 8;   // 1024 packed int32 words per row
static constexpr int NTHR    = 512;
static constexpr int O_PER_IT = 2;
static constexpr int ITERS   = 14;          // 28 columns per block
static constexpr int NBLK    = 1024;        // 1024*28 = 28672

// mode: 0 = bf16, 1 = fp16, 2 = f32
__device__ __forceinline__ float dec16(uint16_t u, int mode) {
  if (mode == 0) {
    union { uint32_t i; float f; } v; v.i = ((uint32_t)u) << 16; return v.f;
  } else {
    union { uint16_t u; _Float16 h; } v; v.u = u; return (float)v.h;
  }
}

// --- dtype sniffer (verbatim from verified R3) ---
__global__ void sniff_kernel(const uint16_t* __restrict__ x, int* __restrict__ flag) {
  const int t = threadIdx.x;
  int ce = 0, co = 0;
  for (int i = t; i < 4096; i += 64) {
    const uint16_t ue = x[2*i];
    const uint16_t uo = x[2*i + 1];
    const int ee = (ue >> 7) & 0xFF;
    const int eo = (uo >> 7) & 0xFF;
    if (ee >= 118 && ee <= 131) ce++;
    if (eo >= 118 && eo <= 131) co++;
  }
  for (int d = 32; d; d >>= 1) {
    ce += __shfl_xor(ce, d);
    co += __shfl_xor(co, d);
  }
  if (t == 0) {
    int mode;
    if (ce > 2867 && co > 2867)      mode = 0;   // bf16
    else if (co > 2867)              mode = 2;   // f32
    else                             mode = 1;   // fp16
    *flag = mode;
  }
}

__global__ __launch_bounds__(NTHR, 1)
void wq_main_kernel(const uint16_t* __restrict__ x16,
                    const uint32_t* __restrict__ qweight,
                    const uint32_t* __restrict__ qzeros,
                    const uint16_t* __restrict__ sc16,
                    const uint16_t* __restrict__ b16,
                    void* __restrict__ outv,
                    const int* __restrict__ flag)
{
  __shared__ float lds[O_PER_IT][M_ROWS][NTHR];   // 32 KB
  const int mode = *flag;                         // uniform
  const int t = threadIdx.x;
  const float* xF  = (const float*)x16;
  const float* scF = (const float*)sc16;
  const float* bF  = (const float*)b16;

  // x fragment: thread owns k in [16t, 16t+16), all 8 rows, f32, scalar loads
  float xf[M_ROWS][16];
  {
    const int kbase = 16 * t;
    if (mode == 2) {
      #pragma unroll
      for (int n = 0; n < M_ROWS; ++n)
        #pragma unroll
        for (int i = 0; i < 16; ++i)
          xf[n][i] = xF[(size_t)n * K_TOT + kbase + i];
    } else {
      #pragma unroll
      for (int n = 0; n < M_ROWS; ++n)
        #pragma unroll
        for (int i = 0; i < 16; ++i)
          xf[n][i] = dec16(x16[(size_t)n * K_TOT + kbase + i], mode);
    }
  }

  const int g = t >> 3, zsh = (g & 7) * 4, zword = g >> 3;

  for (int it = 0; it < ITERS; ++it) {
    const int obase = blockIdx.x * (ITERS * O_PER_IT) + it * O_PER_IT;

    #pragma unroll
    for (int oi = 0; oi < O_PER_IT; ++oi) {
      const int o = obase + oi;
      const uint32_t zw = qzeros[o * 8 + zword];
      const float z = (float)((zw >> zsh) & 15u);
      const float s = (mode == 2) ? scF[o * 64 + g] : dec16(sc16[o * 64 + g], mode);
      const uint32_t w0 = qweight[(size_t)o * KW + 2 * t];
      const uint32_t w1 = qweight[(size_t)o * KW + 2 * t + 1];

      float d[M_ROWS];
      #pragma unroll
      for (int n = 0; n < M_ROWS; ++n) d[n] = 0.f;

      const uint32_t wv[2] = { w0, w1 };
      #pragma unroll
      for (int w = 0; w < 2; ++w) {
        #pragma unroll
        for (int j = 0; j < 8; ++j) {
          const float q   = (float)((wv[w] >> (4 * j)) & 15u);
          const float wgt = s * (q - z);          // exact probe math
          #pragma unroll
          for (int n = 0; n < M_ROWS; ++n)
            d[n] = fmaf(wgt, xf[n][8 * w + j], d[n]);
        }
      }
      #pragma unroll
      for (int n = 0; n < M_ROWS; ++n) lds[oi][n][t] = d[n];
    }
    __syncthreads();

    // reduce: wave handles flattened (oi,n) pairs p = 2*wave, 2*wave+1
    {
      const int wvid = t >> 6, lane = t & 63;
      #pragma unroll
      for (int c = 0; c < 2; ++c) {
        const int p = 2 * wvid + c, oi = p >> 3, n = p & 7;
        float v = 0.f;
        #pragma unroll
        for (int i = 0; i < 8; ++i) v += lds[oi][n][lane + 64 * i];
        v += __shfl_xor(v, 32);
        v += __shfl_xor(v, 16);
        v += __shfl_xor(v, 8);
        v += __shfl_xor(v, 4);
        v += __shfl_xor(v, 2);
        v += __shfl_xor(v, 1);
        if (lane == 0) {
          const int o = obase + oi;
          const float b = (mode == 2) ? bF[o] : dec16(b16[o], mode);
          const float r = v + b;
          const size_t idx = (size_t)n * O_TOT + o;
          if (mode == 0) {
            ((__hip_bfloat16*)outv)[idx] = __float2bfloat16(r);
          } else if (mode == 1) {
            union { uint16_t u; _Float16 h; } cc; cc.h = (_Float16)r;
            ((uint16_t*)outv)[idx] = cc.u;
          } else {
            ((float*)outv)[idx] = r;
          }
        }
      }
    }
    __syncthreads();
  }
}

extern "C" void kernel_launch(void* const* d_in, const int* in_sizes, int n_in,
                              void* d_out, int out_size, void* d_ws, size_t ws_size,
                              hipStream_t stream)
{
  const uint16_t* x       = (const uint16_t*)d_in[0];
  const uint32_t* qweight = (const uint32_t*)d_in[1];
  const uint32_t* qzeros  = (const uint32_t*)d_in[2];
  const uint16_t* scales  = (const uint16_t*)d_in[3];
  const uint16_t* bias    = (const uint16_t*)d_in[4];
  int* flag = (int*)d_ws;

  hipLaunchKernelGGL(sniff_kernel, dim3(1), dim3(64), 0, stream, x, flag);
  hipLaunchKernelGGL(wq_main_kernel, dim3(NBLK), dim3(NTHR), 0, stream,
                     x, qweight, qzeros, scales, bias, d_out, flag);
}

// Round 5
// 119.128 us; speedup vs baseline: 26.0715x; 1.3636x over previous
//
#include <hip/hip_runtime.h>
#include <hip/hip_bf16.h>
#include <stdint.h>

typedef short short8 __attribute__((ext_vector_type(8)));
typedef float f32x4  __attribute__((ext_vector_type(4)));

static constexpr int O_TOT = 28672;
static constexpr int K_TOT = 8192;
static constexpr int M_ROWS = 8;
static constexpr int KW = 1024;            // packed int32 words per output row

// workspace layout
static constexpr size_t WS_FLAG = 0;
static constexpr size_t WS_X    = 4096;                  // 16 rows x 8192 bf16 (rows 8..15 zero) = 256KB
static constexpr size_t WS_SG   = WS_X + 16 * 8192 * 2;  // 64 groups x 8 rows f32 = 2KB
static constexpr size_t WS_NEED = WS_SG + 64 * 8 * 4 + 64;

// mode: 0 = bf16, 1 = fp16, 2 = f32
__device__ __forceinline__ float dec16(uint16_t u, int mode) {
  if (mode == 0) {
    union { uint32_t i; float f; } v; v.i = ((uint32_t)u) << 16; return v.f;
  } else {
    union { uint16_t u; _Float16 h; } v; v.u = u; return (float)v.h;
  }
}
__device__ __forceinline__ uint16_t f2bf_bits(float f) {
  union { __hip_bfloat16 b; uint16_t u; } v; v.b = __float2bfloat16(f); return v.u;
}

// --- dtype sniffer (verbatim, verified R3/R4) ---
__global__ void sniff_kernel(const uint16_t* __restrict__ x, int* __restrict__ flag) {
  const int t = threadIdx.x;
  int ce = 0, co = 0;
  for (int i = t; i < 4096; i += 64) {
    const uint16_t ue = x[2*i];
    const uint16_t uo = x[2*i + 1];
    const int ee = (ue >> 7) & 0xFF;
    const int eo = (uo >> 7) & 0xFF;
    if (ee >= 118 && ee <= 131) ce++;
    if (eo >= 118 && eo <= 131) co++;
  }
  for (int d = 32; d; d >>= 1) { ce += __shfl_xor(ce, d); co += __shfl_xor(co, d); }
  if (t == 0) {
    int mode;
    if (ce > 2867 && co > 2867)      mode = 0;
    else if (co > 2867)              mode = 2;
    else                             mode = 1;
    *flag = mode;
  }
}

// --- prep: decode x -> bf16 ws (permuted within 8-blocks: 0,4,1,5,2,6,3,7), zero rows 8..15 ---
__global__ void prep_kernel(const uint16_t* __restrict__ x16, uint8_t* __restrict__ ws,
                            const int* __restrict__ flag) {
  const int mode = *flag;
  const float* xF = (const float*)x16;
  uint16_t* xb = (uint16_t*)(ws + WS_X);
  const int tid = blockIdx.x * 256 + threadIdx.x;   // 64 blocks x 256 = 16384
  #pragma unroll
  for (int i = 0; i < 4; ++i) {
    const int e = tid * 4 + i;                      // 0..65535
    const int r = e >> 13, k = e & 8191;
    const float v = (mode == 2) ? xF[(size_t)r * K_TOT + k]
                                : dec16(x16[(size_t)r * K_TOT + k], mode);
    const int j = k & 7, wb = k >> 3;
    const int dp = ((j & 3) << 1) | (j >> 2);       // dest position within 8-block
    xb[(size_t)r * K_TOT + wb * 8 + dp] = f2bf_bits(v);
  }
  uint32_t* zr = (uint32_t*)(ws + WS_X + (size_t)8 * K_TOT * 2);
  zr[tid * 2 + 0] = 0;
  zr[tid * 2 + 1] = 0;                              // rows 8..15 zeroed (128KB)
}

// --- sg: per-(row,group) sums of the staged bf16 x ---
__global__ void sg_kernel(uint8_t* __restrict__ ws) {
  const int p = blockIdx.x * 64 + threadIdx.x;      // 8 blocks x 64 = 512
  const int r = p & 7, G = p >> 3;
  const uint16_t* xb = (const uint16_t*)(ws + WS_X) + (size_t)r * K_TOT + G * 128;
  float s = 0.f;
  for (int i = 0; i < 128; ++i) s += dec16(xb[i], 0);
  ((float*)(ws + WS_SG))[G * 8 + r] = s;
}

// --- main MFMA kernel: wave owns 16 output cols x full K ---
__global__ __launch_bounds__(256)
void wq_mfma_kernel(const uint32_t* __restrict__ qweight,
                    const uint32_t* __restrict__ qzeros,
                    const uint16_t* __restrict__ sc16,
                    const uint16_t* __restrict__ b16,
                    void* __restrict__ outv,
                    const uint8_t* __restrict__ ws,
                    const int* __restrict__ flag)
{
  const int mode = *flag;
  const float* scF = (const float*)sc16;
  const float* bF  = (const float*)b16;
  const int t = threadIdx.x, wid = t >> 6, lane = t & 63;
  const int tile = blockIdx.x * 4 + wid;
  const int c    = lane & 15;          // A-row AND B-col index (lane&15)
  const int g4   = lane >> 4;          // k-slot group
  const int cg   = tile * 16 + c;      // global output column

  const uint16_t* xb  = (const uint16_t*)(ws + WS_X);
  const float*    sgp = (const float*)(ws + WS_SG);
  const uint32_t* qp  = qweight + (size_t)cg * KW;
  const uint4*  abase = (const uint4*)(xb + (size_t)c * K_TOT);  // uint4 idx == qweight word idx
  const int base0 = 4 * g4;

  f32x4 D = {0.f, 0.f, 0.f, 0.f};

  // prologue: load super-step 0
  uint4 q0 = *(const uint4*)(qp + base0);
  uint4 a0[4], a1[4]; uint4 q1;
  #pragma unroll
  for (int u = 0; u < 4; ++u) a0[u] = abase[base0 + u];

#define GBODY(TT, QC, AC, QN, AN)                                              \
  do {                                                                         \
    const int Tn = ((TT) < 63) ? (TT) + 1 : 63;                                \
    QN = *(const uint4*)(qp + 16 * Tn + base0);                                \
    AN[0] = abase[16 * Tn + base0 + 0];                                        \
    AN[1] = abase[16 * Tn + base0 + 1];                                        \
    AN[2] = abase[16 * Tn + base0 + 2];                                        \
    AN[3] = abase[16 * Tn + base0 + 3];                                        \
    f32x4 tmp = {0.f, 0.f, 0.f, 0.f};                                          \
    const uint32_t wv[4] = {QC.x, QC.y, QC.z, QC.w};                           \
    _Pragma("unroll")                                                          \
    for (int u = 0; u < 4; ++u) {                                              \
      const uint32_t w = wv[u];                                                \
      union { uint32_t d[4]; short8 s; } bb;                                   \
      bb.d[0] = ( w        & 0x000F000Fu) | 0x43004300u;                       \
      bb.d[1] = ((w >> 4)  & 0x000F000Fu) | 0x43004300u;                       \
      bb.d[2] = ((w >> 8)  & 0x000F000Fu) | 0x43004300u;                       \
      bb.d[3] = ((w >> 12) & 0x000F000Fu) | 0x43004300u;                       \
      union { uint4 q; short8 s; } aa; aa.q = AC[u];                           \
      tmp = __builtin_amdgcn_mfma_f32_16x16x32_bf16(aa.s, bb.s, tmp, 0, 0, 0); \
    }                                                                          \
    const uint32_t zw = qzeros[cg * 8 + ((TT) >> 3)];                          \
    const float zf = (float)((zw >> (((TT) & 7) * 4)) & 15u);                  \
    const float sv = (mode == 2) ? scF[cg * 64 + (TT)]                         \
                                 : dec16(sc16[cg * 64 + (TT)], mode);          \
    const float c128z = 128.0f + zf;                                           \
    if (g4 < 2) {                                                              \
      f32x4 sgv = *(const f32x4*)(sgp + (TT) * 8 + g4 * 4);                    \
      D[0] += sv * (tmp[0] - c128z * sgv[0]);                                  \
      D[1] += sv * (tmp[1] - c128z * sgv[1]);                                  \
      D[2] += sv * (tmp[2] - c128z * sgv[2]);                                  \
      D[3] += sv * (tmp[3] - c128z * sgv[3]);                                  \
    }                                                                          \
  } while (0)

  for (int T = 0; T < 64; T += 2) {
    GBODY(T,     q0, a0, q1, a1);
    GBODY(T + 1, q1, a1, q0, a0);
  }
#undef GBODY

  if (g4 < 2) {
    const float b = (mode == 2) ? bF[cg] : dec16(b16[cg], mode);
    #pragma unroll
    for (int reg = 0; reg < 4; ++reg) {
      const int r = g4 * 4 + reg;                  // D row = (lane>>4)*4 + reg (m89)
      const float v = D[reg] + b;
      const size_t idx = (size_t)r * O_TOT + cg;
      if (mode == 0)      ((__hip_bfloat16*)outv)[idx] = __float2bfloat16(v);
      else if (mode == 1) { union { uint16_t u; _Float16 h; } cc; cc.h = (_Float16)v;
                            ((uint16_t*)outv)[idx] = cc.u; }
      else                ((float*)outv)[idx] = v;
    }
  }
}

// --- verified R4 fallback (used only if ws too small) ---
static constexpr int NTHR = 512, O_PER_IT = 2, ITERS = 14, NBLK = 1024;
__global__ __launch_bounds__(NTHR, 1)
void wq_fallback_kernel(const uint16_t* __restrict__ x16,
                        const uint32_t* __restrict__ qweight,
                        const uint32_t* __restrict__ qzeros,
                        const uint16_t* __restrict__ sc16,
                        const uint16_t* __restrict__ b16,
                        void* __restrict__ outv,
                        const int* __restrict__ flag)
{
  __shared__ float lds[O_PER_IT][M_ROWS][NTHR];
  const int mode = *flag;
  const int t = threadIdx.x;
  const float* xF  = (const float*)x16;
  const float* scF = (const float*)sc16;
  const float* bF  = (const float*)b16;
  float xf[M_ROWS][16];
  {
    const int kbase = 16 * t;
    if (mode == 2) {
      #pragma unroll
      for (int n = 0; n < M_ROWS; ++n)
        #pragma unroll
        for (int i = 0; i < 16; ++i) xf[n][i] = xF[(size_t)n * K_TOT + kbase + i];
    } else {
      #pragma unroll
      for (int n = 0; n < M_ROWS; ++n)
        #pragma unroll
        for (int i = 0; i < 16; ++i) xf[n][i] = dec16(x16[(size_t)n * K_TOT + kbase + i], mode);
    }
  }
  const int g = t >> 3, zsh = (g & 7) * 4, zword = g >> 3;
  for (int it = 0; it < ITERS; ++it) {
    const int obase = blockIdx.x * (ITERS * O_PER_IT) + it * O_PER_IT;
    #pragma unroll
    for (int oi = 0; oi < O_PER_IT; ++oi) {
      const int o = obase + oi;
      const uint32_t zw = qzeros[o * 8 + zword];
      const float z = (float)((zw >> zsh) & 15u);
      const float s = (mode == 2) ? scF[o * 64 + g] : dec16(sc16[o * 64 + g], mode);
      const uint32_t w0 = qweight[(size_t)o * KW + 2 * t];
      const uint32_t w1 = qweight[(size_t)o * KW + 2 * t + 1];
      float d[M_ROWS];
      #pragma unroll
      for (int n = 0; n < M_ROWS; ++n) d[n] = 0.f;
      const uint32_t wv[2] = { w0, w1 };
      #pragma unroll
      for (int w = 0; w < 2; ++w)
        #pragma unroll
        for (int j = 0; j < 8; ++j) {
          const float q = (float)((wv[w] >> (4 * j)) & 15u);
          const float wgt = s * (q - z);
          #pragma unroll
          for (int n = 0; n < M_ROWS; ++n) d[n] = fmaf(wgt, xf[n][8 * w + j], d[n]);
        }
      #pragma unroll
      for (int n = 0; n < M_ROWS; ++n) lds[oi][n][t] = d[n];
    }
    __syncthreads();
    {
      const int wvid = t >> 6, lanei = t & 63;
      #pragma unroll
      for (int cc2 = 0; cc2 < 2; ++cc2) {
        const int p = 2 * wvid + cc2, oi = p >> 3, n = p & 7;
        float v = 0.f;
        #pragma unroll
        for (int i = 0; i < 8; ++i) v += lds[oi][n][lanei + 64 * i];
        v += __shfl_xor(v, 32); v += __shfl_xor(v, 16); v += __shfl_xor(v, 8);
        v += __shfl_xor(v, 4);  v += __shfl_xor(v, 2);  v += __shfl_xor(v, 1);
        if (lanei == 0) {
          const int o = obase + oi;
          const float b = (mode == 2) ? bF[o] : dec16(b16[o], mode);
          const float r = v + b;
          const size_t idx = (size_t)n * O_TOT + o;
          if (mode == 0)      ((__hip_bfloat16*)outv)[idx] = __float2bfloat16(r);
          else if (mode == 1) { union { uint16_t u; _Float16 h; } cc; cc.h = (_Float16)r;
                                ((uint16_t*)outv)[idx] = cc.u; }
          else                ((float*)outv)[idx] = r;
        }
      }
    }
    __syncthreads();
  }
}

extern "C" void kernel_launch(void* const* d_in, const int* in_sizes, int n_in,
                              void* d_out, int out_size, void* d_ws, size_t ws_size,
                              hipStream_t stream)
{
  const uint16_t* x       = (const uint16_t*)d_in[0];
  const uint32_t* qweight = (const uint32_t*)d_in[1];
  const uint32_t* qzeros  = (const uint32_t*)d_in[2];
  const uint16_t* scales  = (const uint16_t*)d_in[3];
  const uint16_t* bias    = (const uint16_t*)d_in[4];
  int* flag = (int*)d_ws;

  hipLaunchKernelGGL(sniff_kernel, dim3(1), dim3(64), 0, stream, x, flag);

  if (ws_size >= WS_NEED) {
    uint8_t* ws = (uint8_t*)d_ws;
    hipLaunchKernelGGL(prep_kernel, dim3(64), dim3(256), 0, stream, x, ws, flag);
    hipLaunchKernelGGL(sg_kernel,   dim3(8),  dim3(64),  0, stream, ws);
    hipLaunchKernelGGL(wq_mfma_kernel, dim3(448), dim3(256), 0, stream,
                       qweight, qzeros, scales, bias, d_out, ws, flag);
  } else {
    hipLaunchKernelGGL(wq_fallback_kernel, dim3(NBLK), dim3(NTHR), 0, stream,
                       x, qweight, qzeros, scales, bias, d_out, flag);
  }
}